// Round 11
// baseline (88.739 us; speedup 1.0000x reference)
//
#include <hip/hip_runtime.h>
#include <cstdint>
#include <cstddef>

typedef float v16f __attribute__((ext_vector_type(16)));
typedef short v8s  __attribute__((ext_vector_type(8)));

#define MFMA32(A,B,C) __builtin_amdgcn_mfma_f32_32x32x16_bf16((A),(B),(C),0,0,0)
#define THRU 1e-3f

__device__ __forceinline__ unsigned f2bf(float f) {
  unsigned u = __builtin_bit_cast(unsigned, f);
  u += 0x7FFFu + ((u >> 16) & 1u);
  return u >> 16;
}
__device__ __forceinline__ float bf2f(unsigned us) {
  return __builtin_bit_cast(float, us << 16);
}

// ---------------------------------------------------------------------------
// prep: h = x @ W^T + b (f32 vector GEMM); bf16 h/m splits of x in MFMA-tiled
// layout frag[b][t=node/32][kc][lane]{16B}; EFl per-i {El,Fl}; EFh head-major
// per-j {Er,Fr}; h stored as PV-B-FRAGMENT tiles vt[b][h][jt][f][lane]{8bf16}:
// lane&31 = c-col, element e at k = f*16 + (lane>>5)*8 + e  (j = jt*32 + k).
// ---------------------------------------------------------------------------
__global__ __launch_bounds__(256) void gat_prep(
    const float* __restrict__ nf, const float* __restrict__ Wm,
    const float* __restrict__ bias, const float* __restrict__ aw,
    unsigned short* __restrict__ nfh, unsigned short* __restrict__ nfm,
    unsigned short* __restrict__ vt,
    float* __restrict__ EFl, float* __restrict__ EFh)
{
  __shared__ float xl[32][132];
  const int tid = threadIdx.x;
  const int row = tid & 31, g = tid >> 5;
  const int r0 = blockIdx.x * 32;          // global node row base (0..8191)
  const int b = r0 >> 11, n0 = r0 & 2047;
  const int d0 = g * 16;

  float x[16];
  {
    const float* xp = nf + (size_t)(r0 + row) * 128 + d0;
#pragma unroll
    for (int q = 0; q < 4; ++q) {
      float4 v = *(const float4*)(xp + 4 * q);
      x[4*q+0] = v.x; x[4*q+1] = v.y; x[4*q+2] = v.z; x[4*q+3] = v.w;
    }
  }
  {
    unsigned hu[16], mu[16];
#pragma unroll
    for (int q = 0; q < 16; ++q) {
      xl[row][d0 + q] = x[q];
      unsigned hb = f2bf(x[q]); float hf = bf2f(hb);
      unsigned mb = f2bf(x[q] - hf);
      hu[q] = hb; mu[q] = mb;
    }
    // tiled fragment store: (b, t=n0>>5, kc=g, lane=row); cols 0-7 -> lane row
    // (offset row*8), cols 8-15 -> lane 32+row (offset row*8 + 256).
    const size_t to = ((size_t)(b * 64 + (n0 >> 5)) * 8 + g) * 512 + row * 8;
    uint4 p0, p1;
    p0.x = hu[0] | (hu[1] << 16);  p0.y = hu[2] | (hu[3] << 16);
    p0.z = hu[4] | (hu[5] << 16);  p0.w = hu[6] | (hu[7] << 16);
    p1.x = hu[8] | (hu[9] << 16);  p1.y = hu[10] | (hu[11] << 16);
    p1.z = hu[12] | (hu[13] << 16); p1.w = hu[14] | (hu[15] << 16);
    *(uint4*)(nfh + to) = p0; *(uint4*)(nfh + to + 256) = p1;
    p0.x = mu[0] | (mu[1] << 16);  p0.y = mu[2] | (mu[3] << 16);
    p0.z = mu[4] | (mu[5] << 16);  p0.w = mu[6] | (mu[7] << 16);
    p1.x = mu[8] | (mu[9] << 16);  p1.y = mu[10] | (mu[11] << 16);
    p1.z = mu[12] | (mu[13] << 16); p1.w = mu[14] | (mu[15] << 16);
    *(uint4*)(nfm + to) = p0; *(uint4*)(nfm + to + 256) = p1;
  }
  __syncthreads();

  float acc[16];
  const int ob = g * 16;
#pragma unroll
  for (int o = 0; o < 16; ++o) acc[o] = bias[ob + o];
  for (int dd = 0; dd < 128; dd += 4) {
    float4 xq = *(const float4*)&xl[row][dd];
#pragma unroll
    for (int o = 0; o < 16; ++o) {
      float4 wq = *(const float4*)(Wm + (size_t)(ob + o) * 128 + dd);
      acc[o] = fmaf(xq.x, wq.x, acc[o]);
      acc[o] = fmaf(xq.y, wq.y, acc[o]);
      acc[o] = fmaf(xq.z, wq.z, acc[o]);
      acc[o] = fmaf(xq.w, wq.w, acc[o]);
    }
  }
  // PV-B-fragment store: j=n0+row; f=(row>>4)&1, kh=(row>>3)&1, e=row&7
  {
    const int f = (row >> 4) & 1, kh = (row >> 3) & 1, e = row & 7;
#pragma unroll
    for (int o = 0; o < 16; ++o) {
      const int c = ob + o, hh2 = c >> 5, cc = c & 31;
      const size_t va = (((size_t)(b * 4 + hh2) * 64 + (n0 >> 5)) * 2 + f) * 512
                        + (kh * 32 + cc) * 8 + e;
      vt[va] = (unsigned short)f2bf(acc[o]);
    }
  }

  const int hh = g >> 1, cb = (g & 1) * 16;
  float sl = 0.f, sr = 0.f;
#pragma unroll
  for (int o = 0; o < 16; ++o) {
    sl = fmaf(acc[o], aw[hh * 64 + cb + o], sl);
    sr = fmaf(acc[o], aw[hh * 64 + 32 + cb + o], sr);
  }
  sl += __shfl_xor(sl, 32, 64);
  sr += __shfl_xor(sr, 32, 64);
  if (!(g & 1)) {
    const float L2E = 1.4426950408889634f;
    float El = exp2f(sl * L2E), Fl = exp2f(sl * (0.3f * L2E));
    float Er = exp2f(sr * L2E), Fr = exp2f(sr * (0.3f * L2E));
    size_t nn = (size_t)(r0 + row);
    EFl[nn * 8 + hh]     = El;
    EFl[nn * 8 + 4 + hh] = Fl;
    const size_t eo = ((size_t)(b * 4 + hh) * 2048 + (n0 + row)) * 2;
    EFh[eo]     = Er;
    EFh[eo + 1] = Fr;
  }
}

// ---------------------------------------------------------------------------
// mask: S = 3-pass split-bf16 (hh+hm+mh) from TILED fragments (coalesced 1KB
// loads). Lanes with any |S|<THR recompute the exact f64 dot INLINE and patch
// their sign bit before the single mask-word store. Zero atomics, no list.
// mask layout: u32 mask[b][j>>5][i], bit = j&31.   (unchanged from round 9)
// ---------------------------------------------------------------------------
__global__ __launch_bounds__(256) void gat_mask(
    const unsigned short* __restrict__ nfh, const unsigned short* __restrict__ nfm,
    const float* __restrict__ nf, unsigned* __restrict__ mask)
{
  const int tid = threadIdx.x, lane = tid & 63;
  const int li = lane & 31, hi = lane >> 5;
  const int blk = blockIdx.x;
  const int jb = blk & 31, t = blk >> 5;
  const int ib = t & 15, b = t >> 4;
  const int i0 = ib * 128 + (tid >> 6) * 32;
  const int j0 = jb * 64;

  const size_t lbyte = (size_t)lane * 8;
  const size_t tiB  = ((size_t)(b * 64 + (i0 >> 5)) * 8) * 512 + lbyte;
  const size_t tjA0 = ((size_t)(b * 64 + (j0 >> 5)) * 8) * 512 + lbyte;
  const size_t tjA1 = tjA0 + 4096;

  v8s BH[8], BM[8];
#pragma unroll
  for (int kc = 0; kc < 8; ++kc) {
    BH[kc] = *(const v8s*)(nfh + tiB + kc * 512);
    BM[kc] = *(const v8s*)(nfm + tiB + kc * 512);
  }

  v16f S0, S1;
#pragma unroll
  for (int r = 0; r < 16; ++r) { S0[r] = 0.f; S1[r] = 0.f; }
#pragma unroll
  for (int kc = 0; kc < 8; ++kc) {
    v8s A0h = *(const v8s*)(nfh + tjA0 + kc * 512);
    v8s A1h = *(const v8s*)(nfh + tjA1 + kc * 512);
    v8s A0m = *(const v8s*)(nfm + tjA0 + kc * 512);
    v8s A1m = *(const v8s*)(nfm + tjA1 + kc * 512);
    S0 = MFMA32(A0h, BH[kc], S0);
    S1 = MFMA32(A1h, BH[kc], S1);
    S0 = MFMA32(A0h, BM[kc], S0);
    S1 = MFMA32(A1h, BM[kc], S1);
    S0 = MFMA32(A0m, BH[kc], S0);
    S1 = MFMA32(A1m, BH[kc], S1);
  }

  unsigned u0 = 0, u1 = 0;
  float mn = 1e30f;
  const int sh = hi * 4;
#pragma unroll
  for (int r = 0; r < 16; ++r) {
    const int jlc = (r & 3) + 8 * (r >> 2);
    const unsigned bit = (1u << jlc) << sh;
    if (S0[r] > 0.f) u0 |= bit;
    if (S1[r] > 0.f) u1 |= bit;
    mn = fminf(mn, fabsf(S0[r]));
    mn = fminf(mn, fabsf(S1[r]));
  }

  if (mn < THRU) {
    const float* xi = nf + ((size_t)b * 2048 + i0 + li) * 128;
#pragma unroll
    for (int sub = 0; sub < 2; ++sub) {
#pragma unroll
      for (int r = 0; r < 16; ++r) {
        const float s = sub ? S1[r] : S0[r];
        if (fabsf(s) < THRU) {
          const int jlc = (r & 3) + 8 * (r >> 2);
          const int j = j0 + sub * 32 + jlc + 4 * hi;
          const float* xj = nf + ((size_t)b * 2048 + j) * 128;
          double a = 0.0;
          for (int k = 0; k < 128; k += 2) {
            a = fma((double)xi[k],     (double)xj[k],     a);
            a = fma((double)xi[k + 1], (double)xj[k + 1], a);
          }
          const unsigned bit = (1u << jlc) << sh;
          if (sub == 0) u0 = (a > 0.0) ? (u0 | bit) : (u0 & ~bit);
          else          u1 = (a > 0.0) ? (u1 | bit) : (u1 & ~bit);
        }
      }
    }
  }

  unsigned f0 = u0 | (unsigned)__shfl_xor((int)u0, 32, 64);
  unsigned f1 = u1 | (unsigned)__shfl_xor((int)u1, 32, 64);
  if (hi == 0) {
    mask[(size_t)(b * 64 + jb * 2)     * 2048 + i0 + li] = f0;
    mask[(size_t)(b * 64 + jb * 2 + 1) * 2048 + i0 + li] = f1;
  }
}

// ---------------------------------------------------------------------------
// attn: block = 32 i x 1 head; 4 waves split j (512 each, 16 tiles).
// MAIN LOOP IS LDS-FREE AND BARRIER-FREE: V = 2 coalesced dwordx4 B-fragment
// loads from vt; EF = 1 aligned float4 broadcast load per rp (L1-resident);
// mask word per tile from L2. End: 4-way LDS tree combine, divide, write out.
// LDS: 2 slots x 64 x 17 floats = 8704 B.
// ---------------------------------------------------------------------------
__global__ __launch_bounds__(256) void gat_attn(
    const unsigned short* __restrict__ vt, const float* __restrict__ EFl,
    const float* __restrict__ EFh, const unsigned* __restrict__ mask,
    float* __restrict__ out)
{
  __shared__ __align__(16) float sm[2][64][17];
  const int tid = threadIdx.x, lane = tid & 63, wv = tid >> 6;
  const int li = lane & 31, hi = lane >> 5;

  const int blk = blockIdx.x;
  const int ig = blk & 63;
  const int combo = blk >> 6;          // 0..15
  const int b = combo >> 2, h = combo & 3;

  const size_t nb = (size_t)b * 2048;
  const int i0 = ig * 32;

  const float EL = EFl[(nb + i0 + li) * 8 + h];
  const float FL = EFl[(nb + i0 + li) * 8 + 4 + h];

  const unsigned* mrow = mask + (size_t)(b * 64 + wv * 16) * 2048 + i0 + li;
  const float* efb = EFh + ((size_t)(b * 4 + h) * 2048 + wv * 512) * 2;
  const unsigned short* vb =
      vt + ((size_t)(b * 4 + h) * 64 + wv * 16) * 1024 + (size_t)lane * 8;

  v16f acc;
#pragma unroll
  for (int r = 0; r < 16; ++r) acc[r] = 0.f;
  float den0 = 0.f, den1 = 0.f;

#pragma unroll 4
  for (int it2 = 0; it2 < 16; ++it2) {
    const unsigned mh = mrow[(size_t)it2 * 2048] >> (hi * 4);
    v8s V0 = *(const v8s*)(vb + it2 * 1024);
    v8s V1 = *(const v8s*)(vb + it2 * 1024 + 512);
    unsigned pw[8];
#pragma unroll
    for (int rp = 0; rp < 8; ++rp) {
      const int r0 = 2 * rp;
      const int jl0c = (r0 & 3) + 8 * (r0 >> 2);       // even
      const int j2 = it2 * 32 + jl0c + 4 * hi;          // even -> 16B aligned
      float4 e01 = *(const float4*)(efb + j2 * 2);      // {Er0,Fr0,Er1,Fr1}
      const bool m0 = (mh >> jl0c) & 1;
      const bool m1 = (mh >> (jl0c + 1)) & 1;
      float w0 = fmaxf(e01.x * EL, e01.y * FL); w0 = m0 ? w0 : 0.f;
      float w1 = fmaxf(e01.z * EL, e01.w * FL); w1 = m1 ? w1 : 0.f;
      den0 += w0; den1 += w1;
      asm("v_cvt_pk_bf16_f32 %0, %1, %2" : "=v"(pw[rp]) : "v"(w0), "v"(w1));
    }
    auto q0 = __builtin_amdgcn_permlane32_swap((int)pw[0], (int)pw[2], false, false);
    auto q1 = __builtin_amdgcn_permlane32_swap((int)pw[1], (int)pw[3], false, false);
    auto q2 = __builtin_amdgcn_permlane32_swap((int)pw[4], (int)pw[6], false, false);
    auto q3 = __builtin_amdgcn_permlane32_swap((int)pw[5], (int)pw[7], false, false);
    uint4 c0, c1;
    c0.x = (unsigned)q0[0]; c0.y = (unsigned)q1[0];
    c0.z = (unsigned)q0[1]; c0.w = (unsigned)q1[1];
    c1.x = (unsigned)q2[0]; c1.y = (unsigned)q3[0];
    c1.z = (unsigned)q2[1]; c1.w = (unsigned)q3[1];
    v8s P0 = __builtin_bit_cast(v8s, c0);
    v8s P1 = __builtin_bit_cast(v8s, c1);
    acc = MFMA32(P0, V0, acc);
    acc = MFMA32(P1, V1, acc);
  }
  float den = den0 + den1;

  // ---- 4-way tree combine in LDS ----
  __syncthreads();
  if (wv >= 2) {
    float* d = &sm[wv - 2][lane][0];
#pragma unroll
    for (int r = 0; r < 16; ++r) d[r] = acc[r];
    d[16] = den;
  }
  __syncthreads();
  if (wv < 2) {
    const float* s = &sm[wv][lane][0];
#pragma unroll
    for (int r = 0; r < 16; ++r) acc[r] += s[r];
    den += s[16];
  }
  __syncthreads();
  if (wv == 1) {
    float* d = &sm[0][lane][0];
#pragma unroll
    for (int r = 0; r < 16; ++r) d[r] = acc[r];
    d[16] = den;
  }
  __syncthreads();
  if (wv == 0) {
    const float* s = &sm[0][lane][0];
#pragma unroll
    for (int r = 0; r < 16; ++r) acc[r] += s[r];
    den += s[16];
    den += __shfl_xor(den, 32, 64);
    float* dl = &sm[1][0][0];        // 32-entry den broadcast table
    if (lane < 32) dl[li] = den;
    asm volatile("s_waitcnt lgkmcnt(0)" ::: "memory");
    __builtin_amdgcn_sched_barrier(0);
    const size_t ob = (nb + i0) * 128 + h * 32 + li;
#pragma unroll
    for (int r = 0; r < 16; ++r) {
      const int il = (r & 3) + 8 * (r >> 2) + 4 * hi;
      out[ob + (size_t)il * 128] = acc[r] / dl[il];
    }
  }
}

// ---------------------------------------------------------------------------
extern "C" void kernel_launch(void* const* d_in, const int* in_sizes, int n_in,
                              void* d_out, int out_size, void* d_ws, size_t ws_size,
                              hipStream_t stream) {
  const float* nf   = (const float*)d_in[0];
  const float* Wm   = (const float*)d_in[1];
  const float* bias = (const float*)d_in[2];
  const float* aw   = (const float*)d_in[3];
  float* out = (float*)d_out;
  char* ws = (char*)d_ws;

  // layout (bytes)
  unsigned short* nfh = (unsigned short*)(ws);             // 2,097,152 (tiled)
  unsigned short* nfm = (unsigned short*)(ws + 2097152);   // 2,097,152 (tiled)
  unsigned short* vt  = (unsigned short*)(ws + 4194304);   // 2,097,152 (B-frag)
  float*    EFl  = (float*)(ws + 6291456);                 //   262,144
  float*    EFh  = (float*)(ws + 6553600);                 //   262,144
  unsigned* mask = (unsigned*)(ws + 6815744);              // 2,097,152

  gat_prep<<<256, 256, 0, stream>>>(nf, Wm, bias, aw, nfh, nfm, vt, EFl, EFh);
  gat_mask<<<2048, 256, 0, stream>>>(nfh, nfm, nf, mask);
  gat_attn<<<1024, 256, 0, stream>>>(vt, EFl, EFh, mask, out);
}

// Round 12
// 76.242 us; speedup vs baseline: 1.1639x; 1.1639x over previous
//
#include <hip/hip_runtime.h>
#include <cstdint>
#include <cstddef>

typedef float v16f __attribute__((ext_vector_type(16)));
typedef short v8s  __attribute__((ext_vector_type(8)));

#define MFMA32(A,B,C) __builtin_amdgcn_mfma_f32_32x32x16_bf16((A),(B),(C),0,0,0)
#define THRU 1e-3f

__device__ __forceinline__ unsigned f2bf(float f) {
  unsigned u = __builtin_bit_cast(unsigned, f);
  u += 0x7FFFu + ((u >> 16) & 1u);
  return u >> 16;
}
__device__ __forceinline__ float bf2f(unsigned us) {
  return __builtin_bit_cast(float, us << 16);
}
__device__ __forceinline__ void gload16(const void* g, void* l) {
  __builtin_amdgcn_global_load_lds(
      (const __attribute__((address_space(1))) void*)g,
      (__attribute__((address_space(3))) void*)l, 16, 0, 0);
}

// ---------------------------------------------------------------------------
// prep (round-8 verbatim): h = x @ W^T + b; bf16 h/m splits of x in MFMA-tiled
// layout frag[b][t=node/32][kc][lane]{16B}; EFl per-i {El,Fl}; EFrp head-pair
// {Er,Fr,Er',Fr'}; ht transposed bf16.
// ---------------------------------------------------------------------------
__global__ __launch_bounds__(256) void gat_prep(
    const float* __restrict__ nf, const float* __restrict__ Wm,
    const float* __restrict__ bias, const float* __restrict__ aw,
    unsigned short* __restrict__ nfh, unsigned short* __restrict__ nfm,
    unsigned short* __restrict__ ht,
    float* __restrict__ EFl, float* __restrict__ EFrp)
{
  __shared__ float xl[32][132];
  const int tid = threadIdx.x;
  const int row = tid & 31, g = tid >> 5;
  const int r0 = blockIdx.x * 32;          // global node row base (0..8191)
  const int b = r0 >> 11, n0 = r0 & 2047;
  const int d0 = g * 16;

  float x[16];
  {
    const float* xp = nf + (size_t)(r0 + row) * 128 + d0;
#pragma unroll
    for (int q = 0; q < 4; ++q) {
      float4 v = *(const float4*)(xp + 4 * q);
      x[4*q+0] = v.x; x[4*q+1] = v.y; x[4*q+2] = v.z; x[4*q+3] = v.w;
    }
  }
  {
    unsigned hu[16], mu[16];
#pragma unroll
    for (int q = 0; q < 16; ++q) {
      xl[row][d0 + q] = x[q];
      unsigned hb = f2bf(x[q]); float hf = bf2f(hb);
      unsigned mb = f2bf(x[q] - hf);
      hu[q] = hb; mu[q] = mb;
    }
    // tiled fragment store: (b, t=n0>>5, kc=g, lane=row)
    const size_t to = ((size_t)(b * 64 + (n0 >> 5)) * 8 + g) * 512 + row * 8;
    uint4 p0, p1;
    p0.x = hu[0] | (hu[1] << 16);  p0.y = hu[2] | (hu[3] << 16);
    p0.z = hu[4] | (hu[5] << 16);  p0.w = hu[6] | (hu[7] << 16);
    p1.x = hu[8] | (hu[9] << 16);  p1.y = hu[10] | (hu[11] << 16);
    p1.z = hu[12] | (hu[13] << 16); p1.w = hu[14] | (hu[15] << 16);
    *(uint4*)(nfh + to) = p0; *(uint4*)(nfh + to + 256) = p1;
    p0.x = mu[0] | (mu[1] << 16);  p0.y = mu[2] | (mu[3] << 16);
    p0.z = mu[4] | (mu[5] << 16);  p0.w = mu[6] | (mu[7] << 16);
    p1.x = mu[8] | (mu[9] << 16);  p1.y = mu[10] | (mu[11] << 16);
    p1.z = mu[12] | (mu[13] << 16); p1.w = mu[14] | (mu[15] << 16);
    *(uint4*)(nfm + to) = p0; *(uint4*)(nfm + to + 256) = p1;
  }
  __syncthreads();

  float acc[16];
  const int ob = g * 16;
#pragma unroll
  for (int o = 0; o < 16; ++o) acc[o] = bias[ob + o];
  for (int dd = 0; dd < 128; dd += 4) {
    float4 xq = *(const float4*)&xl[row][dd];
#pragma unroll
    for (int o = 0; o < 16; ++o) {
      float4 wq = *(const float4*)(Wm + (size_t)(ob + o) * 128 + dd);
      acc[o] = fmaf(xq.x, wq.x, acc[o]);
      acc[o] = fmaf(xq.y, wq.y, acc[o]);
      acc[o] = fmaf(xq.z, wq.z, acc[o]);
      acc[o] = fmaf(xq.w, wq.w, acc[o]);
    }
  }
#pragma unroll
  for (int o = 0; o < 16; ++o)
    ht[((size_t)b * 128 + ob + o) * 2048 + n0 + row] = (unsigned short)f2bf(acc[o]);

  const int hh = g >> 1, cb = (g & 1) * 16;
  float sl = 0.f, sr = 0.f;
#pragma unroll
  for (int o = 0; o < 16; ++o) {
    sl = fmaf(acc[o], aw[hh * 64 + cb + o], sl);
    sr = fmaf(acc[o], aw[hh * 64 + 32 + cb + o], sr);
  }
  sl += __shfl_xor(sl, 32, 64);
  sr += __shfl_xor(sr, 32, 64);
  if (!(g & 1)) {
    const float L2E = 1.4426950408889634f;
    float El = exp2f(sl * L2E), Fl = exp2f(sl * (0.3f * L2E));
    float Er = exp2f(sr * L2E), Fr = exp2f(sr * (0.3f * L2E));
    size_t nn = (size_t)(r0 + row);
    EFl[nn * 8 + hh]     = El;
    EFl[nn * 8 + 4 + hh] = Fl;
    // head-pair layout: {Er(2p), Fr(2p), Er(2p+1), Fr(2p+1)} per 16B
    EFrp[nn * 8 + (hh >> 1) * 4 + (hh & 1) * 2]     = Er;
    EFrp[nn * 8 + (hh >> 1) * 4 + (hh & 1) * 2 + 1] = Fr;
  }
}

// ---------------------------------------------------------------------------
// mask (r9-verified): S = 3-pass split-bf16 from TILED fragments (coalesced
// 1KB loads). Lanes with any |S|<THR recompute exact f64 dot INLINE and patch
// their sign bit. Zero atomics, no list, no separate fix kernel.
// mask layout: u32 mask[b][j>>5][i], bit = j&31.
// ---------------------------------------------------------------------------
__global__ __launch_bounds__(256) void gat_mask(
    const unsigned short* __restrict__ nfh, const unsigned short* __restrict__ nfm,
    const float* __restrict__ nf, unsigned* __restrict__ mask)
{
  const int tid = threadIdx.x, lane = tid & 63;
  const int li = lane & 31, hi = lane >> 5;
  const int blk = blockIdx.x;
  const int jb = blk & 31, t = blk >> 5;
  const int ib = t & 15, b = t >> 4;
  const int i0 = ib * 128 + (tid >> 6) * 32;
  const int j0 = jb * 64;

  const size_t lbyte = (size_t)lane * 8;
  const size_t tiB  = ((size_t)(b * 64 + (i0 >> 5)) * 8) * 512 + lbyte;
  const size_t tjA0 = ((size_t)(b * 64 + (j0 >> 5)) * 8) * 512 + lbyte;
  const size_t tjA1 = tjA0 + 4096;

  v8s BH[8], BM[8];
#pragma unroll
  for (int kc = 0; kc < 8; ++kc) {
    BH[kc] = *(const v8s*)(nfh + tiB + kc * 512);
    BM[kc] = *(const v8s*)(nfm + tiB + kc * 512);
  }

  v16f S0, S1;
#pragma unroll
  for (int r = 0; r < 16; ++r) { S0[r] = 0.f; S1[r] = 0.f; }
#pragma unroll
  for (int kc = 0; kc < 8; ++kc) {
    v8s A0h = *(const v8s*)(nfh + tjA0 + kc * 512);
    v8s A1h = *(const v8s*)(nfh + tjA1 + kc * 512);
    v8s A0m = *(const v8s*)(nfm + tjA0 + kc * 512);
    v8s A1m = *(const v8s*)(nfm + tjA1 + kc * 512);
    S0 = MFMA32(A0h, BH[kc], S0);
    S1 = MFMA32(A1h, BH[kc], S1);
    S0 = MFMA32(A0h, BM[kc], S0);
    S1 = MFMA32(A1h, BM[kc], S1);
    S0 = MFMA32(A0m, BH[kc], S0);
    S1 = MFMA32(A1m, BH[kc], S1);
  }

  unsigned u0 = 0, u1 = 0;
  float mn = 1e30f;
  const int sh = hi * 4;
#pragma unroll
  for (int r = 0; r < 16; ++r) {
    const int jlc = (r & 3) + 8 * (r >> 2);
    const unsigned bit = (1u << jlc) << sh;
    if (S0[r] > 0.f) u0 |= bit;
    if (S1[r] > 0.f) u1 |= bit;
    mn = fminf(mn, fabsf(S0[r]));
    mn = fminf(mn, fabsf(S1[r]));
  }

  if (mn < THRU) {
    const float* xi = nf + ((size_t)b * 2048 + i0 + li) * 128;
#pragma unroll
    for (int sub = 0; sub < 2; ++sub) {
#pragma unroll
      for (int r = 0; r < 16; ++r) {
        const float s = sub ? S1[r] : S0[r];
        if (fabsf(s) < THRU) {
          const int jlc = (r & 3) + 8 * (r >> 2);
          const int j = j0 + sub * 32 + jlc + 4 * hi;
          const float* xj = nf + ((size_t)b * 2048 + j) * 128;
          double a = 0.0;
          for (int k = 0; k < 128; k += 2) {
            a = fma((double)xi[k],     (double)xj[k],     a);
            a = fma((double)xi[k + 1], (double)xj[k + 1], a);
          }
          const unsigned bit = (1u << jlc) << sh;
          if (sub == 0) u0 = (a > 0.0) ? (u0 | bit) : (u0 & ~bit);
          else          u1 = (a > 0.0) ? (u1 | bit) : (u1 & ~bit);
        }
      }
    }
  }

  unsigned f0 = u0 | (unsigned)__shfl_xor((int)u0, 32, 64);
  unsigned f1 = u1 | (unsigned)__shfl_xor((int)u1, 32, 64);
  if (hi == 0) {
    mask[(size_t)(b * 64 + jb * 2)     * 2048 + i0 + li] = f0;
    mask[(size_t)(b * 64 + jb * 2 + 1) * 2048 + i0 + li] = f1;
  }
}

// ---------------------------------------------------------------------------
// attn (round-8 verbatim — best measured): head-pair split, double-buffered
// gload_lds staging, barrier per 128-j half, mask words prefetched to regs.
// LDS: 2 x (V 16384 granule-XOR | EF 2048) = 36864.
// ---------------------------------------------------------------------------
#define PVBLK(pw, h, smv)                                                      \
  {                                                                            \
    auto q0 = __builtin_amdgcn_permlane32_swap((int)pw[0], (int)pw[2], false, false); \
    auto q1 = __builtin_amdgcn_permlane32_swap((int)pw[1], (int)pw[3], false, false); \
    auto q2 = __builtin_amdgcn_permlane32_swap((int)pw[4], (int)pw[6], false, false); \
    auto q3 = __builtin_amdgcn_permlane32_swap((int)pw[5], (int)pw[7], false, false); \
    uint4 c0, c1;                                                              \
    c0.x = (unsigned)q0[0]; c0.y = (unsigned)q1[0];                            \
    c0.z = (unsigned)q0[1]; c0.w = (unsigned)q1[1];                            \
    c1.x = (unsigned)q2[0]; c1.y = (unsigned)q3[0];                            \
    c1.z = (unsigned)q2[1]; c1.w = (unsigned)q3[1];                            \
    v8s P0 = __builtin_bit_cast(v8s, c0);                                      \
    v8s P1 = __builtin_bit_cast(v8s, c1);                                      \
    const int cc = (h) * 32 + li;                                              \
    const char* vr = (smv) + cc * 256;                                         \
    const int cx = cc & 15;                                                    \
    v8s V0 = *(const v8s*)(vr + ((((it2 << 2) + hi) ^ cx) << 4));              \
    v8s V1 = *(const v8s*)(vr + ((((it2 << 2) + 2 + hi) ^ cx) << 4));          \
    acc[h] = MFMA32(P0, V0, acc[h]);                                           \
    acc[h] = MFMA32(P1, V1, acc[h]);                                           \
  }

template<int CH>
__global__ __launch_bounds__(256, 2) void gat_attn(
    const unsigned short* __restrict__ ht, const float* __restrict__ EFl,
    const float* __restrict__ EFrp, const unsigned* __restrict__ mask,
    float* __restrict__ nump, float* __restrict__ denp)
{
  constexpr int JPC = 2048 / CH;       // j per chunk
  constexpr int H = JPC >> 7;          // 128-j halves
  constexpr int MW = JPC >> 5;         // mask words per (i-lane)
  __shared__ __align__(16) char sm[2][18432];   // V 16K | EF 2K each

  const int tid = threadIdx.x, lane = tid & 63, wv = tid >> 6;
  const int li = lane & 31, hi = lane >> 5;

  // XCD swizzle: blocks sharing (b,ch,hp2) — same V/EF chunk — on one XCD.
  const int blk = blockIdx.x;
  const int x = blk & 7, y = blk >> 3;
  const int ig = y & 15;
  const int combo = x * CH + (y >> 4);       // 0..8*CH-1
  const int hp2 = combo & 1;                 // head pair (heads 2hp2, 2hp2+1)
  const int r2 = combo >> 1;
  const int ch = r2 % CH, b = r2 / CH;

  const size_t nb = (size_t)b * 2048;
  const int i0 = ig * 128 + wv * 32;
  const int j0 = ch * JPC;

  float EL[2], FL[2];
  {
    const float* p = EFl + (nb + i0 + li) * 8 + 2 * hp2;
    float2 e = *(const float2*)p;
    float2 f = *(const float2*)(p + 4);
    EL[0] = e.x; EL[1] = e.y; FL[0] = f.x; FL[1] = f.y;
  }

  // prefetch ALL mask words for this wave's i-rows x full j-range
  unsigned mw[MW];
#pragma unroll
  for (int q = 0; q < MW; ++q)
    mw[q] = mask[(size_t)(b * 64 + (j0 >> 5) + q) * 2048 + i0 + li] >> (hi * 4);

  v16f acc[2];
#pragma unroll
  for (int h = 0; h < 2; ++h)
#pragma unroll
    for (int r = 0; r < 16; ++r) acc[h][r] = 0.f;
  float den[2] = {0.f, 0.f};

  auto STAGE = [&](int h0, int p) {
    const int jbase = j0 + (h0 << 7);
    const size_t cbase = (size_t)b * 128 + (hp2 << 6);
#pragma unroll
    for (int s = 0; s < 4; ++s) {
      const int L = s * 4096 + tid * 16;
      const int c = L >> 8, gs = (L >> 4) & 15;
      const int g = gs ^ (c & 15);
      gload16((const char*)ht + (((cbase + c) * 2048 + jbase) << 1) + (g << 4),
              sm[p] + L);
    }
    if (tid < 128)   // EF: 128 j-nodes x 16B = 2KB
      gload16((const char*)EFrp + (size_t)(nb + jbase + tid) * 32 + (hp2 << 4),
              sm[p] + 16384 + tid * 16);
  };

  STAGE(0, 0);
  __syncthreads();   // drain prologue stage

#pragma unroll
  for (int h0 = 0; h0 < H; ++h0) {
    const int p = h0 & 1;
    if (h0) __syncthreads();           // drains stage(h0) issued last iter
    if (h0 + 1 < H) STAGE(h0 + 1, p ^ 1);   // in flight across compute

#pragma unroll
    for (int it2 = 0; it2 < 4; ++it2) {
      const char* Eb = sm[p] + 16384 + (it2 << 9);
      const unsigned mh = mw[(h0 << 2) + it2];
      unsigned pA[8], pB[8];
#pragma unroll
      for (int rp = 0; rp < 8; ++rp) {
        const int r0 = 2 * rp;
        const int jl0c = (r0 & 3) + 8 * (r0 >> 2);
        const int nA = (jl0c + 4 * hi) * 16;
        float4 e0 = *(const float4*)(Eb + nA);        // {Er0,Fr0,Er1,Fr1}
        float4 e1 = *(const float4*)(Eb + nA + 16);   // node jl0c+1
        const bool m0 = (mh >> jl0c) & 1;
        const bool m1 = (mh >> (jl0c + 1)) & 1;
        float wA0 = fmaxf(e0.x * EL[0], e0.y * FL[0]); wA0 = m0 ? wA0 : 0.f;
        float wB0 = fmaxf(e0.z * EL[1], e0.w * FL[1]); wB0 = m0 ? wB0 : 0.f;
        float wA1 = fmaxf(e1.x * EL[0], e1.y * FL[0]); wA1 = m1 ? wA1 : 0.f;
        float wB1 = fmaxf(e1.z * EL[1], e1.w * FL[1]); wB1 = m1 ? wB1 : 0.f;
        den[0] += wA0 + wA1;
        den[1] += wB0 + wB1;
        asm("v_cvt_pk_bf16_f32 %0, %1, %2" : "=v"(pA[rp]) : "v"(wA0), "v"(wA1));
        asm("v_cvt_pk_bf16_f32 %0, %1, %2" : "=v"(pB[rp]) : "v"(wB0), "v"(wB1));
      }
      PVBLK(pA, 0, sm[p])
      PVBLK(pB, 1, sm[p])
    }
  }

#pragma unroll
  for (int h = 0; h < 2; ++h) den[h] += __shfl_xor(den[h], 32, 64);

  const size_t obase = ((size_t)b * CH + ch) * 2048 + i0;
#pragma unroll
  for (int h = 0; h < 2; ++h) {
#pragma unroll
    for (int r = 0; r < 16; ++r) {
      const int il = (r & 3) + 8 * (r >> 2) + 4 * hi;
      nump[(obase + il) * 128 + (hp2 * 2 + h) * 32 + li] = acc[h][r];
    }
  }
  if (lane < 32) {
    float2 dv; dv.x = den[0]; dv.y = den[1];
    *(float2*)(denp + (obase + li) * 4 + 2 * hp2) = dv;
  }
}

// ---------------------------------------------------------------------------
// reduce: out = (sum_ch num) / (sum_ch den), float4-vectorized.
// 262144 threads, each handles 4 consecutive cols of one (b,n) row.
// ---------------------------------------------------------------------------
__global__ __launch_bounds__(256) void gat_reduce(
    const float* __restrict__ nump, const float* __restrict__ denp,
    float* __restrict__ out, const int CH)
{
  const int t = blockIdx.x * 256 + threadIdx.x;   // < 262144
  const int b = t >> 16;
  const int rem = t & 65535;
  const int n = rem >> 5;
  const int col = (rem & 31) * 4;
  const int h = col >> 5;
  float4 s = make_float4(0.f, 0.f, 0.f, 0.f);
  float d = 0.f;
  for (int ch = 0; ch < CH; ++ch) {
    const size_t rb = ((size_t)b * CH + ch) * 2048 + n;
    float4 v = *(const float4*)(nump + rb * 128 + col);
    s.x += v.x; s.y += v.y; s.z += v.z; s.w += v.w;
    d += denp[rb * 4 + h];
  }
  float4 o;
  o.x = s.x / d; o.y = s.y / d; o.z = s.z / d; o.w = s.w / d;
  *(float4*)(out + (size_t)t * 4) = o;
}

// ---------------------------------------------------------------------------
extern "C" void kernel_launch(void* const* d_in, const int* in_sizes, int n_in,
                              void* d_out, int out_size, void* d_ws, size_t ws_size,
                              hipStream_t stream) {
  const float* nf   = (const float*)d_in[0];
  const float* Wm   = (const float*)d_in[1];
  const float* bias = (const float*)d_in[2];
  const float* aw   = (const float*)d_in[3];
  float* out = (float*)d_out;
  char* ws = (char*)d_ws;

  // layout (bytes)
  unsigned short* nfh  = (unsigned short*)(ws);            // 2,097,152 (tiled)
  unsigned short* nfm  = (unsigned short*)(ws + 2097152);  // 2,097,152 (tiled)
  unsigned short* ht   = (unsigned short*)(ws + 4194304);  // 2,097,152
  float*    EFl  = (float*)(ws + 6291456);                 //   262,144
  float*    EFrp = (float*)(ws + 6553600);                 //   262,144
  unsigned* mask = (unsigned*)(ws + 6815744);              // 2,097,152
  const size_t o_den = 8912896;

  // need(CH) = o_den + CH*(4194304 + 131072); CH=8 preferred
  int CH = 8;
  if (ws_size < o_den + 8ull * 4325376ull) CH = 4;

  float* denp = (float*)(ws + o_den);
  float* nump = (float*)(ws + o_den + (size_t)CH * 131072);

  gat_prep<<<256, 256, 0, stream>>>(nf, Wm, bias, aw, nfh, nfm, ht, EFl, EFrp);
  gat_mask<<<2048, 256, 0, stream>>>(nfh, nfm, nf, mask);
  if (CH == 8)
    gat_attn<8><<<1024, 256, 0, stream>>>(ht, EFl, EFrp, mask, nump, denp);
  else
    gat_attn<4><<<512, 256, 0, stream>>>(ht, EFl, EFrp, mask, nump, denp);
  gat_reduce<<<1024, 256, 0, stream>>>(nump, denp, out, CH);
}